// Round 3
// baseline (147.475 us; speedup 1.0000x reference)
//
#include <hip/hip_runtime.h>
#include <hip/hip_bf16.h>

// HSTU block for MI355X (gfx950).  B=4, N=1024, D=512, H=8, Dv=Dq=64.
//
// R11 = R10 with the attn bias-gather pathology fixed:
//   - bias table stored TRANSPOSED: bias_t[b][j][i] (prep change)
//   - attn bias loads now coalesced (lane = i = contiguous), 16 ushort
//     loads/subtile (~2 transactions each) instead of 8x 64-transaction
//     gathers per tile
//   - bias folded into silu input (s + bias) instead of MFMA acc-init, so
//     the loads issued before the staging barriers are consumed after the
//     QK MFMA chain (free latency hiding, no extra buffering)
// Attn structure otherwise = R10: swapped S^T = mfma_32x32x16(K,Q), P
// lane-local via cvt_pk + permlane32_swap, Q register-resident, 128-row
// blocks with wave-disjoint 32-row i-stripes, grid (32,4,4).
//
//   Kp  prep_kernel   : fused {uvqk->bf16^T, o_w->bf16^T, nx=LN(x)->bf16, bias_t}
//   K2  gemm1_kernel  : silu(nx @ uvqk) -> u, q/k ([b,h,n,d]), v^T/N ([b,h,d,n])
//   K3  attn_kernel   : S^T=K q^T; P=silu(S+bias) causal; ao+=P@(v/N)
//   K4  ln_mul_kernel : g = u * LN_a(sum of 4 ao partials) -> bf16
//   K5  gemm2_kernel  : out = g @ o_w + o_b + x
//
// cm == triu(k=1) (inline), pm all-false (ignored).

typedef __attribute__((ext_vector_type(8))) short short8;
typedef __attribute__((ext_vector_type(4))) short bf4;
typedef __attribute__((ext_vector_type(4))) float floatx4;
typedef __attribute__((ext_vector_type(16))) float floatx16;

#define MFMA_BF16 __builtin_amdgcn_mfma_f32_16x16x32_bf16
#define MFMA32 __builtin_amdgcn_mfma_f32_32x32x16_bf16

static __device__ __forceinline__ short f2bf(float f) {
  unsigned u = __builtin_bit_cast(unsigned, f);
  u = (u + 0x7fffu + ((u >> 16) & 1u)) >> 16;
  return (short)u;
}
// packed f32x2 -> bf16x2 (v_cvt_pk_bf16_f32 on gfx950)
static __device__ __forceinline__ unsigned pk_bf16(float a, float b) {
  __hip_bfloat162 h = __float22bfloat162_rn(float2{a, b});
  unsigned u;
  __builtin_memcpy(&u, &h, 4);
  return u;
}
static __device__ __forceinline__ short lo16(unsigned u) { return (short)(u & 0xffffu); }
static __device__ __forceinline__ short hi16(unsigned u) { return (short)(u >> 16); }
static __device__ __forceinline__ float bf2f(short s) {
  unsigned u = ((unsigned)(unsigned short)s) << 16;
  return __builtin_bit_cast(float, u);
}
static __device__ __forceinline__ float silu_f(float x) {
  return x / (1.f + __expf(-x));
}
// swap a's upper 32 lanes with b's lower 32 lanes (v_permlane32_swap_b32)
static __device__ __forceinline__ void permswap(unsigned& a, unsigned& b) {
#if __has_builtin(__builtin_amdgcn_permlane32_swap)
  typedef __attribute__((ext_vector_type(2))) unsigned uint2v;
  uint2v r = __builtin_amdgcn_permlane32_swap(a, b, false, false);
  a = r[0];
  b = r[1];
#else
  asm volatile("v_permlane32_swap_b32 %0, %1" : "+v"(a), "+v"(b));
#endif
}
static __device__ __forceinline__ short8 mk8(unsigned a, unsigned b, unsigned c,
                                             unsigned d) {
  union {
    unsigned u[4];
    short8 s;
  } r;
  r.u[0] = a;
  r.u[1] = b;
  r.u[2] = c;
  r.u[3] = d;
  return r.s;
}
// async global->LDS, 16B/lane; LDS dest = wave-uniform base + lane*16
static __device__ __forceinline__ void gl_lds16(const void* g, void* l) {
  __builtin_amdgcn_global_load_lds(
      (const __attribute__((address_space(1))) unsigned int*)g,
      (__attribute__((address_space(3))) unsigned int*)l, 16, 0, 0);
}

// ---------------- Kp: fused prep (bias_t | ln_x | cvt uvqk | cvt o_w) --------
__global__ __launch_bounds__(256) void prep_kernel(
    const float* __restrict__ x, const int* __restrict__ ts,
    const float* __restrict__ uvqk, const float* __restrict__ o_w,
    const float* __restrict__ ln_x_w, const float* __restrict__ ln_x_b,
    const float* __restrict__ ts_w, const float* __restrict__ pos_w,
    short* __restrict__ nx, short* __restrict__ uvqk_t,
    short* __restrict__ o_wt, short* __restrict__ bias) {
  __shared__ float tile[32][33];
  const int id = blockIdx.x;
  const int t = threadIdx.x;
  if (id < 4096) {
    // ---- bias_t[b][j][i] = pos_w[j-i+1023] + ts_w[bucket(ts[min(i+1,1023)]-ts[j])]
    // one block per (b, j); lanes sweep i (coalesced in i)
    const int b = id >> 10, j = id & 1023;
    const int tsj = ts[(b << 10) + j];
    const int i0 = t * 4;
    int4 ti = *(const int4*)&ts[(b << 10) + i0];  // ts[i0 .. i0+3]
    const int* tip = (const int*)&ti;
    int tlast = ts[(b << 10) + ((i0 + 4 <= 1023) ? i0 + 4 : 1023)];
    int te[4] = {tip[1], tip[2], tip[3], tlast};  // ts[min(i+1,1023)]
    float ov[4];
#pragma unroll
    for (int e = 0; e < 4; ++e) {
      int dt = te[e] - tsj;
      float ad = fabsf((float)dt);
      if (ad < 1.f) ad = 1.f;
      int bkt = (int)(__logf(ad) * (1.f / 0.301f));
      if (bkt > 64) bkt = 64;
      ov[e] = pos_w[j - (i0 + e) + 1023] + ts_w[bkt];
    }
    uint2 o2 = {pk_bf16(ov[0], ov[1]), pk_bf16(ov[2], ov[3])};
    *(uint2*)&bias[((size_t)id << 10) + i0] = o2;
  } else if (id < 5120) {
    // ---- nx = LN(x), one wave per 512-row
    const int lane = t & 63;
    const int row = ((id - 4096) << 2) + (t >> 6);
    const int c0 = lane * 8;
    const float* xr = x + (size_t)row * 512;
    float v[8];
    *(float4*)&v[0] = *(const float4*)(xr + c0);
    *(float4*)&v[4] = *(const float4*)(xr + c0 + 4);
    float s = 0.f, sq = 0.f;
#pragma unroll
    for (int e = 0; e < 8; ++e) { s += v[e]; sq += v[e] * v[e]; }
#pragma unroll
    for (int off = 32; off > 0; off >>= 1) {
      s += __shfl_xor(s, off);
      sq += __shfl_xor(sq, off);
    }
    float m = s * (1.f / 512.f);
    float var = sq * (1.f / 512.f) - m * m;
    float rinv = rsqrtf(var + 1e-5f);
    float wv[8], bv[8];
    *(float4*)&wv[0] = *(const float4*)(ln_x_w + c0);
    *(float4*)&wv[4] = *(const float4*)(ln_x_w + c0 + 4);
    *(float4*)&bv[0] = *(const float4*)(ln_x_b + c0);
    *(float4*)&bv[4] = *(const float4*)(ln_x_b + c0 + 4);
    float o[8];
#pragma unroll
    for (int e = 0; e < 8; ++e) o[e] = (v[e] - m) * rinv * wv[e] + bv[e];
    uint4 o4 = {pk_bf16(o[0], o[1]), pk_bf16(o[2], o[3]),
                pk_bf16(o[4], o[5]), pk_bf16(o[6], o[7])};
    *(uint4*)(nx + (size_t)row * 512 + c0) = o4;
  } else {
    // ---- f32 -> bf16 transpose (uvqk: 512x2048 -> 2048x512; o_w: 512x512)
    const float* src; short* dst; int R, C, bc, br;
    if (id < 6144) {
      int idm = id - 5120;
      src = uvqk; dst = uvqk_t; R = 512; C = 2048;
      bc = (idm & 63) * 32; br = (idm >> 6) * 32;
    } else {
      int idm = id - 6144;
      src = o_w; dst = o_wt; R = 512; C = 512;
      bc = (idm & 15) * 32; br = (idm >> 4) * 32;
    }
    const int c = t & 31, r0 = t >> 5;
#pragma unroll
    for (int p = 0; p < 4; ++p) {
      int r = r0 + p * 8;
      tile[r][c] = src[(size_t)(br + r) * C + bc + c];
    }
    __syncthreads();
#pragma unroll
    for (int p = 0; p < 4; ++p) {
      int r = r0 + p * 8;
      dst[(size_t)(bc + r) * R + br + c] = f2bf(tile[c][r]);
    }
  }
}

// ---------------- K2: GEMM1 128x128 tile, BK=64 as 2x32 chunks ---------------
__global__ __launch_bounds__(256) void gemm1_kernel(
    const short* __restrict__ A, const short* __restrict__ Bt,
    short* __restrict__ u_buf, short* __restrict__ vt_buf,
    short* __restrict__ q_buf, short* __restrict__ k_buf) {
  __shared__ __align__(16) short As[2][128 * 32];
  __shared__ __align__(16) short Bs[2][128 * 32];
  const int t = threadIdx.x;
  const int lane = t & 63, w = t >> 6;
  const int quad = lane >> 4, l15 = lane & 15;
  const int m0 = blockIdx.x * 128, n0 = blockIdx.y * 128;
  const int wm = (w & 1) * 64, wn = (w >> 1) * 64;
  const int lr = lane >> 2, lc = (lane & 3) * 8;
  floatx4 acc[4][4];
#pragma unroll
  for (int i = 0; i < 4; ++i)
#pragma unroll
    for (int j = 0; j < 4; ++j) acc[i][j] = (floatx4){0.f, 0.f, 0.f, 0.f};

  for (int k0 = 0; k0 < 512; k0 += 64) {
    __syncthreads();
#pragma unroll
    for (int c = 0; c < 2; ++c)
#pragma unroll
      for (int p = 0; p < 2; ++p) {
        int ra = w * 32 + p * 16;
        gl_lds16(&A[(size_t)(m0 + ra + lr) * 512 + k0 + c * 32 + lc], &As[c][ra * 32]);
        gl_lds16(&Bt[(size_t)(n0 + ra + lr) * 512 + k0 + c * 32 + lc], &Bs[c][ra * 32]);
      }
    __syncthreads();
#pragma unroll
    for (int c = 0; c < 2; ++c) {
      short8 af[4], bfr[4];
#pragma unroll
      for (int mi = 0; mi < 4; ++mi) af[mi] = *(const short8*)&As[c][(wm + mi * 16 + l15) * 32 + quad * 8];
#pragma unroll
      for (int ni = 0; ni < 4; ++ni) bfr[ni] = *(const short8*)&Bs[c][(wn + ni * 16 + l15) * 32 + quad * 8];
#pragma unroll
      for (int mi = 0; mi < 4; ++mi)
#pragma unroll
        for (int ni = 0; ni < 4; ++ni)
          acc[mi][ni] = MFMA_BF16(af[mi], bfr[ni], acc[mi][ni], 0, 0, 0);
    }
  }
  const int seg = n0 >> 9, cbase = n0 & 511;
  if (seg == 0) {  // u: [row][512] bf16
#pragma unroll
    for (int mi = 0; mi < 4; ++mi)
#pragma unroll
      for (int ni = 0; ni < 4; ++ni) {
        int row0 = m0 + wm + mi * 16 + quad * 4;
        int c = cbase + wn + ni * 16 + l15;
        float v0 = silu_f(acc[mi][ni][0]), v1 = silu_f(acc[mi][ni][1]);
        float v2 = silu_f(acc[mi][ni][2]), v3 = silu_f(acc[mi][ni][3]);
        unsigned pa = pk_bf16(v0, v1), pb = pk_bf16(v2, v3);
        u_buf[(size_t)row0 * 512 + c] = lo16(pa);
        u_buf[(size_t)(row0 + 1) * 512 + c] = hi16(pa);
        u_buf[(size_t)(row0 + 2) * 512 + c] = lo16(pb);
        u_buf[(size_t)(row0 + 3) * 512 + c] = hi16(pb);
      }
  } else if (seg == 1) {  // v transposed & pre-scaled by 1/N: [b,h,d,n]
#pragma unroll
    for (int mi = 0; mi < 4; ++mi)
#pragma unroll
      for (int ni = 0; ni < 4; ++ni) {
        int c = cbase + wn + ni * 16 + l15;
        int h = c >> 6, d = c & 63;
        int row0 = m0 + wm + mi * 16 + quad * 4;
        int b_ = row0 >> 10, nb = row0 & 1023;
        float v0 = silu_f(acc[mi][ni][0]) * (1.f / 1024.f);
        float v1 = silu_f(acc[mi][ni][1]) * (1.f / 1024.f);
        float v2 = silu_f(acc[mi][ni][2]) * (1.f / 1024.f);
        float v3 = silu_f(acc[mi][ni][3]) * (1.f / 1024.f);
        uint2 sv = {pk_bf16(v0, v1), pk_bf16(v2, v3)};
        *(uint2*)&vt_buf[(((size_t)(b_ * 8 + h) * 64 + d) << 10) + nb] = sv;
      }
  } else {  // q or k: [b,h,n,d]
    short* dst = (seg == 2) ? q_buf : k_buf;
#pragma unroll
    for (int mi = 0; mi < 4; ++mi)
#pragma unroll
      for (int ni = 0; ni < 4; ++ni) {
        int row0 = m0 + wm + mi * 16 + quad * 4;
        int c = cbase + wn + ni * 16 + l15;
        int b_ = row0 >> 10, nb = row0 & 1023;
        size_t base = ((((size_t)(b_ * 8 + (c >> 6))) << 10) + nb) * 64 + (c & 63);
        float v0 = silu_f(acc[mi][ni][0]), v1 = silu_f(acc[mi][ni][1]);
        float v2 = silu_f(acc[mi][ni][2]), v3 = silu_f(acc[mi][ni][3]);
        unsigned pa = pk_bf16(v0, v1), pb = pk_bf16(v2, v3);
        dst[base] = lo16(pa);
        dst[base + 64] = hi16(pa);
        dst[base + 128] = lo16(pb);
        dst[base + 192] = hi16(pb);
      }
  }
}

// ---------------- K3: causal silu-attention, swapped 32x32 MFMA --------------
// grid (32 bh, 4 pair, 4 jh).  Block = 128 i-rows; per staged 64-j tile each
// wave owns a DISJOINT 32-row i-stripe and the full 64 j (two 32x32 S^T
// sub-tiles).  Swapped QK (S^T = K q^T) keeps P lane-local; P -> A-fragments
// via cvt_pk + permlane32_swap.  Q in registers.  Bias read COALESCED from
// bias_t[b][j][i] (lane = i) and added to S before silu.  V pre-scaled by 1/N.
__global__ __launch_bounds__(256, 3) void attn_kernel(
    const short* __restrict__ q_buf, const short* __restrict__ k_buf,
    const short* __restrict__ vt_buf, const short* __restrict__ bias_buf,
    short* __restrict__ ao_part) {
  __shared__ __align__(16) short k_s[64][72];
  __shared__ __align__(16) short vt_s[64][72];

  const int t = threadIdx.x;
  const int lane = t & 63, w = t >> 6;
  const int l31 = lane & 31, hh = lane >> 5, h8 = hh * 8;
  const int bh = blockIdx.x, y4 = blockIdx.y, jh = blockIdx.z;
  const int b = bh >> 3, hd = bh & 7;
  const short* qh = q_buf + (size_t)bh * 65536;
  const short* kh = k_buf + (size_t)bh * 65536;
  const short* vth = vt_buf + (size_t)bh * 65536;
  const short* btb = bias_buf + ((size_t)b << 20);  // bias_t[b][j][i]
  const int sr = t >> 2, sc = (t & 3) * 16;

#pragma unroll
  for (int half = 0; half < 2; ++half) {
    const int it = half ? (7 - y4) : y4;  // 128-row i-tile index
    const int i0 = it * 128;
    const int iw0 = i0 + w * 32;          // this wave's i-stripe base
    const int ig = iw0 + l31;             // this lane's global i (S^T column)
    const int jtmax = 2 * it + 1;         // last 64-j tile touching the diagonal
    // Q fragments (B-operand) in registers: qf[kk] = Q[ig][kk*16 + h8 .. +7]
    short8 qf[4];
#pragma unroll
    for (int kk = 0; kk < 4; ++kk)
      qf[kk] = *(const short8*)&qh[(size_t)ig * 64 + kk * 16 + h8];
    // first j-tile prefetch into registers
    float4 kr0, kr1, vr0, vr1;
    {
      int j0 = jh * 64;
      kr0 = *(const float4*)&kh[(size_t)(j0 + sr) * 64 + sc];
      kr1 = *(const float4*)&kh[(size_t)(j0 + sr) * 64 + sc + 8];
      vr0 = *(const float4*)&vth[(size_t)sr * 1024 + j0 + sc];
      vr1 = *(const float4*)&vth[(size_t)sr * 1024 + j0 + sc + 8];
    }
    floatx16 ao0, ao1;
#pragma unroll
    for (int r = 0; r < 16; ++r) { ao0[r] = 0.f; ao1[r] = 0.f; }

    // helper: S^T 32x32 sub-tile -> +bias, silu/mask -> pack -> PV
    auto sub_tile = [&](const unsigned short* ba, int jcol, int jb,
                        bool needmask) {
      // ---- S^T = K q^T  (acc row = j_local crow(r,hh), col = i) ----
      floatx16 s;
#pragma unroll
      for (int r = 0; r < 16; ++r) s[r] = 0.f;
#pragma unroll
      for (int kk = 0; kk < 4; ++kk) {
        short8 ak = *(const short8*)&k_s[jcol + l31][kk * 16 + h8];
        s = MFMA32(ak, qf[kk], s, 0, 0, 0);
      }
      // ---- P = silu(S + bias), causal (zero where j > i) ----
      float p[16];
#pragma unroll
      for (int r = 0; r < 16; ++r) {
        float xv = s[r] + bf2f((short)ba[r]);
        float pv = xv / (1.f + __expf(-xv));
        if (needmask) {
          int jg = jb + hh * 4 + (r & 3) + 8 * (r >> 2);
          if (jg > ig) pv = 0.f;
        }
        p[r] = pv;
      }
      // ---- P -> bf16 A-fragments (cvt_pk + permlane32_swap) ----
      unsigned X0 = pk_bf16(p[0], p[1]), Y0 = pk_bf16(p[2], p[3]);
      unsigned X1 = pk_bf16(p[4], p[5]), Y1 = pk_bf16(p[6], p[7]);
      unsigned X2 = pk_bf16(p[8], p[9]), Y2 = pk_bf16(p[10], p[11]);
      unsigned X3 = pk_bf16(p[12], p[13]), Y3 = pk_bf16(p[14], p[15]);
      permswap(X0, X1);
      permswap(Y0, Y1);
      permswap(X2, X3);
      permswap(Y2, Y3);
      short8 pa0 = mk8(X0, Y0, X1, Y1);  // k-chunk j_local [0,16)
      short8 pa1 = mk8(X2, Y2, X3, Y3);  // k-chunk j_local [16,32)
      // ---- ao += P @ (v/N) ----
#pragma unroll
      for (int c = 0; c < 2; ++c) {
        short8 pa = c ? pa1 : pa0;
        short8 bv0 = *(const short8*)&vt_s[l31][jcol + c * 16 + h8];
        short8 bv1 = *(const short8*)&vt_s[32 + l31][jcol + c * 16 + h8];
        ao0 = MFMA32(pa, bv0, ao0, 0, 0, 0);
        ao1 = MFMA32(pa, bv1, ao1, 0, 0, 0);
      }
    };

    for (int jt = jh; jt <= jtmax; jt += 4) {
      const int j0a = jt * 64, j0b = j0a + 32;
      const bool live_a = (j0a <= iw0 + 31);
      const bool live_b = (j0b <= iw0 + 31);
      const bool mask_a = live_a && (j0a + 31 > iw0);
      const bool mask_b = live_b && (j0b + 31 > iw0);
      // coalesced bias loads: row j = jb + crow(r,hh), col i = iw0 + l31
      unsigned short ba[16], bb[16];
      if (live_a) {
        const short* bp = btb + (((size_t)(j0a + 4 * hh)) << 10) + iw0 + l31;
#pragma unroll
        for (int r = 0; r < 16; ++r)
          ba[r] = (unsigned short)bp[((size_t)((r & 3) + 8 * (r >> 2))) << 10];
      }
      if (live_b) {
        const short* bp = btb + (((size_t)(j0b + 4 * hh)) << 10) + iw0 + l31;
#pragma unroll
        for (int r = 0; r < 16; ++r)
          bb[r] = (unsigned short)bp[((size_t)((r & 3) + 8 * (r >> 2))) << 10];
      }
      __syncthreads();  // prev tile's k_s/vt_s MFMA reads done
      *(float4*)&k_s[sr][sc] = kr0;
      *(float4*)&k_s[sr][sc + 8] = kr1;
      *(float4*)&vt_s[sr][sc] = vr0;
      *(float4*)&vt_s[sr][sc + 8] = vr1;
      {  // prefetch next tile (clamped redundant reload on last iter)
        int jn = (jt + 4 <= jtmax) ? jt + 4 : jt;
        int jn0 = jn * 64;
        kr0 = *(const float4*)&kh[(size_t)(jn0 + sr) * 64 + sc];
        kr1 = *(const float4*)&kh[(size_t)(jn0 + sr) * 64 + sc + 8];
        vr0 = *(const float4*)&vth[(size_t)sr * 1024 + jn0 + sc];
        vr1 = *(const float4*)&vth[(size_t)sr * 1024 + jn0 + sc + 8];
      }
      __syncthreads();  // staged k_s/vt_s visible
      if (!live_a) continue;  // whole 64-j tile above the diagonal for this wave
      __builtin_amdgcn_s_setprio(1);
      sub_tile(ba, 0, j0a, mask_a);
      if (live_b) sub_tile(bb, 32, j0b, mask_b);
      __builtin_amdgcn_s_setprio(0);
    }
    // ---- epilogue: ao row = i_local crow(r,hh), col = d ----
    short* aod = ao_part + (size_t)jh * 2097152;
#pragma unroll
    for (int r = 0; r < 16; ++r) {
      int gi = iw0 + (r & 3) + 8 * (r >> 2) + 4 * hh;
      size_t base = ((size_t)(b * 1024 + gi)) * 512 + hd * 64 + l31;
      aod[base] = f2bf(ao0[r]);
      aod[base + 32] = f2bf(ao1[r]);
    }
  }
}

// ---------------- K4: g = u * LN_a(ao0+ao1+ao2+ao3) -> bf16 ------------------
__global__ __launch_bounds__(256) void ln_mul_kernel(
    const short* __restrict__ ao_part, const short* __restrict__ u,
    const float* __restrict__ w_, const float* __restrict__ b_,
    short* __restrict__ g) {
  const int lane = threadIdx.x & 63;
  const int row = (blockIdx.x << 2) + (threadIdx.x >> 6);
  const int c0 = lane * 8;
  short8 a0 = *(const short8*)(ao_part + (size_t)row * 512 + c0);
  short8 a1 = *(const short8*)(ao_part + 2097152 + (size_t)row * 512 + c0);
  short8 a2 = *(const short8*)(ao_part + 4194304 + (size_t)row * 512 + c0);
  short8 a3 = *(const short8*)(ao_part + 6291456 + (size_t)row * 512 + c0);
  float v[8];
#pragma unroll
  for (int e = 0; e < 8; ++e)
    v[e] = (bf2f(a0[e]) + bf2f(a1[e])) + (bf2f(a2[e]) + bf2f(a3[e]));
  float s = 0.f, sq = 0.f;
#pragma unroll
  for (int e = 0; e < 8; ++e) { s += v[e]; sq += v[e] * v[e]; }
#pragma unroll
  for (int off = 32; off > 0; off >>= 1) {
    s += __shfl_xor(s, off);
    sq += __shfl_xor(sq, off);
  }
  float m = s * (1.f / 512.f);
  float var = sq * (1.f / 512.f) - m * m;
  float rinv = rsqrtf(var + 1e-5f);
  float wv[8], bv[8];
  *(float4*)&wv[0] = *(const float4*)(w_ + c0);
  *(float4*)&wv[4] = *(const float4*)(w_ + c0 + 4);
  *(float4*)&bv[0] = *(const float4*)(b_ + c0);
  *(float4*)&bv[4] = *(const float4*)(b_ + c0 + 4);
  short8 uv = *(const short8*)(u + (size_t)row * 512 + c0);
  float o[8];
#pragma unroll
  for (int e = 0; e < 8; ++e)
    o[e] = bf2f(uv[e]) * ((v[e] - m) * rinv * wv[e] + bv[e]);
  uint4 o4 = {pk_bf16(o[0], o[1]), pk_bf16(o[2], o[3]),
              pk_bf16(o[4], o[5]), pk_bf16(o[6], o[7])};
  *(uint4*)(g + (size_t)row * 512 + c0) = o4;
}

// ---------------- K5: GEMM2 64x64 tiles, grid 512 ----------------------------
__global__ __launch_bounds__(256) void gemm2_kernel(
    const short* __restrict__ G, const short* __restrict__ Wt,
    const float* __restrict__ o_b, const float* __restrict__ x,
    float* __restrict__ out) {
  __shared__ __align__(16) short As[2][64 * 32];
  __shared__ __align__(16) short Bs[2][64 * 32];
  const int t = threadIdx.x;
  const int lane = t & 63, w = t >> 6;
  const int quad = lane >> 4, l15 = lane & 15;
  const int m0 = blockIdx.x * 64, n0 = blockIdx.y * 64;
  const int lr = lane >> 2, lc = (lane & 3) * 8;
  floatx4 acc[4];
#pragma unroll
  for (int j = 0; j < 4; ++j) acc[j] = (floatx4){0.f, 0.f, 0.f, 0.f};

  for (int k0 = 0; k0 < 512; k0 += 64) {
    __syncthreads();
#pragma unroll
    for (int c = 0; c < 2; ++c) {
      int ra = w * 16;
      gl_lds16(&G[(size_t)(m0 + ra + lr) * 512 + k0 + c * 32 + lc], &As[c][ra * 32]);
      gl_lds16(&Wt[(size_t)(n0 + ra + lr) * 512 + k0 + c * 32 + lc], &Bs[c][ra * 32]);
    }
    __syncthreads();
#pragma unroll
    for (int c = 0; c < 2; ++c) {
      short8 af = *(const short8*)&As[c][(w * 16 + l15) * 32 + quad * 8];
#pragma unroll
      for (int ni = 0; ni < 4; ++ni) {
        short8 bfr = *(const short8*)&Bs[c][(ni * 16 + l15) * 32 + quad * 8];
        acc[ni] = MFMA_BF16(af, bfr, acc[ni], 0, 0, 0);
      }
    }
  }
#pragma unroll
  for (int ni = 0; ni < 4; ++ni)
#pragma unroll
    for (int r = 0; r < 4; ++r) {
      int row = m0 + w * 16 + quad * 4 + r;
      int c = n0 + ni * 16 + l15;
      out[(size_t)row * 512 + c] = acc[ni][r] + o_b[c] + x[(size_t)row * 512 + c];
    }
}

extern "C" void kernel_launch(void* const* d_in, const int* in_sizes, int n_in,
                              void* d_out, int out_size, void* d_ws, size_t ws_size,
                              hipStream_t stream) {
  const float* x = (const float*)d_in[0];
  const int* ts = (const int*)d_in[1];
  // d_in[2] = cm (triu, inline), d_in[3] = pm (all false, ignored)
  const float* uvqk = (const float*)d_in[4];
  const float* o_w = (const float*)d_in[5];
  const float* o_b = (const float*)d_in[6];
  const float* ln_x_w = (const float*)d_in[7];
  const float* ln_x_b = (const float*)d_in[8];
  const float* ln_a_w = (const float*)d_in[9];
  const float* ln_a_b = (const float*)d_in[10];
  const float* ts_w = (const float*)d_in[11];
  const float* pos_w = (const float*)d_in[12];
  float* out = (float*)d_out;

  char* ws = (char*)d_ws;
  short* nx = (short*)(ws + 0);              // 4096x512 bf16 (4 MB); reused as g after gemm1
  short* uvqk_t = (short*)(ws + 4194304);    // 2048x512 bf16 (2 MB)
  short* o_wt = (short*)(ws + 6291456);      // 512x512 bf16 (0.5 MB)
  short* u_buf = (short*)(ws + 6815744);     // 4096x512 bf16 (4 MB)
  short* q_buf = (short*)(ws + 11010048);    // [B,H,N,64] bf16 (4 MB)
  short* k_buf = (short*)(ws + 15204352);    // [B,H,N,64] bf16 (4 MB)
  short* vt_buf = (short*)(ws + 19398656);   // [B,H,64,N] bf16 (4 MB)
  short* bias_buf = (short*)(ws + 23592960); // bias_t [B,N,N] bf16 (8 MB)
  short* ao_part = (short*)(ws + 31981568);  // 4 x [B,N,512] bf16 (16 MB)
  short* g_buf = nx;

  hipLaunchKernelGGL(prep_kernel, dim3(6400), dim3(256), 0, stream,
                     x, ts, uvqk, o_w, ln_x_w, ln_x_b, ts_w, pos_w,
                     nx, uvqk_t, o_wt, bias_buf);
  hipLaunchKernelGGL(gemm1_kernel, dim3(32, 16), dim3(256), 0, stream, nx, uvqk_t, u_buf, vt_buf, q_buf, k_buf);
  hipLaunchKernelGGL(attn_kernel, dim3(32, 4, 4), dim3(256), 0, stream, q_buf, k_buf, vt_buf, bias_buf, ao_part);
  hipLaunchKernelGGL(ln_mul_kernel, dim3(1024), dim3(256), 0, stream, ao_part, u_buf, ln_a_w, ln_a_b, g_buf);
  hipLaunchKernelGGL(gemm2_kernel, dim3(64, 8), dim3(256), 0, stream, g_buf, o_wt, o_b, x, out);
}

// Round 4
// 144.529 us; speedup vs baseline: 1.0204x; 1.0204x over previous
//
#include <hip/hip_runtime.h>
#include <hip/hip_bf16.h>

// HSTU block for MI355X (gfx950).  B=4, N=1024, D=512, H=8, Dv=Dq=64.
//
// R12 = R11 with attn re-parallelized for occupancy (the R8->R10 regression
// was grid 1024->512 blocks = 4->2 blocks/CU; R11 proved bias access pattern
// is immaterial):
//   - block = 64i x 64j per staged tile, 4 waves as 2(i) x 2(j) QUADRANTS,
//     grid (32,8,4) = 1024 blocks, __launch_bounds__(256,4)
//   - each wave: one 32x32 S^T subtile = 4 QK + 4 PV mfma_32x32x16 (swapped
//     operands keep P lane-local; cvt_pk + permlane32_swap; Q in registers)
//   - j-half partial ao's combined via 16KB LDS reduce in the epilogue
//   - bias back to [b][i][j] orientation, folded into QK acc-init (8 VGPR)
//
//   Kp  prep_kernel   : fused {uvqk->bf16^T, o_w->bf16^T, nx=LN(x)->bf16, bias}
//   K2  gemm1_kernel  : silu(nx @ uvqk) -> u, q/k ([b,h,n,d]), v^T/N ([b,h,d,n])
//   K3  attn_kernel   : S^T=bias+K q^T (swapped); P=silu(S) causal; ao+=P@(v/N)
//   K4  ln_mul_kernel : g = u * LN_a(sum of 4 ao partials) -> bf16
//   K5  gemm2_kernel  : out = g @ o_w + o_b + x
//
// cm == triu(k=1) (inline), pm all-false (ignored).

typedef __attribute__((ext_vector_type(8))) short short8;
typedef __attribute__((ext_vector_type(4))) short bf4;
typedef __attribute__((ext_vector_type(4))) float floatx4;
typedef __attribute__((ext_vector_type(16))) float floatx16;

#define MFMA_BF16 __builtin_amdgcn_mfma_f32_16x16x32_bf16
#define MFMA32 __builtin_amdgcn_mfma_f32_32x32x16_bf16

static __device__ __forceinline__ short f2bf(float f) {
  unsigned u = __builtin_bit_cast(unsigned, f);
  u = (u + 0x7fffu + ((u >> 16) & 1u)) >> 16;
  return (short)u;
}
// packed f32x2 -> bf16x2 (v_cvt_pk_bf16_f32 on gfx950)
static __device__ __forceinline__ unsigned pk_bf16(float a, float b) {
  __hip_bfloat162 h = __float22bfloat162_rn(float2{a, b});
  unsigned u;
  __builtin_memcpy(&u, &h, 4);
  return u;
}
static __device__ __forceinline__ short lo16(unsigned u) { return (short)(u & 0xffffu); }
static __device__ __forceinline__ short hi16(unsigned u) { return (short)(u >> 16); }
static __device__ __forceinline__ float bf2f(short s) {
  unsigned u = ((unsigned)(unsigned short)s) << 16;
  return __builtin_bit_cast(float, u);
}
static __device__ __forceinline__ float bflo(unsigned u) {
  return __builtin_bit_cast(float, u << 16);
}
static __device__ __forceinline__ float bfhi(unsigned u) {
  return __builtin_bit_cast(float, u & 0xffff0000u);
}
static __device__ __forceinline__ float silu_f(float x) {
  return x / (1.f + __expf(-x));
}
// swap a's upper 32 lanes with b's lower 32 lanes (v_permlane32_swap_b32)
static __device__ __forceinline__ void permswap(unsigned& a, unsigned& b) {
#if __has_builtin(__builtin_amdgcn_permlane32_swap)
  typedef __attribute__((ext_vector_type(2))) unsigned uint2v;
  uint2v r = __builtin_amdgcn_permlane32_swap(a, b, false, false);
  a = r[0];
  b = r[1];
#else
  asm volatile("v_permlane32_swap_b32 %0, %1" : "+v"(a), "+v"(b));
#endif
}
static __device__ __forceinline__ short8 mk8(unsigned a, unsigned b, unsigned c,
                                             unsigned d) {
  union {
    unsigned u[4];
    short8 s;
  } r;
  r.u[0] = a;
  r.u[1] = b;
  r.u[2] = c;
  r.u[3] = d;
  return r.s;
}
// async global->LDS, 16B/lane; LDS dest = wave-uniform base + lane*16
static __device__ __forceinline__ void gl_lds16(const void* g, void* l) {
  __builtin_amdgcn_global_load_lds(
      (const __attribute__((address_space(1))) unsigned int*)g,
      (__attribute__((address_space(3))) unsigned int*)l, 16, 0, 0);
}

// ---------------- Kp: fused prep (bias | ln_x | cvt uvqk | cvt o_w) ----------
__global__ __launch_bounds__(256) void prep_kernel(
    const float* __restrict__ x, const int* __restrict__ ts,
    const float* __restrict__ uvqk, const float* __restrict__ o_w,
    const float* __restrict__ ln_x_w, const float* __restrict__ ln_x_b,
    const float* __restrict__ ts_w, const float* __restrict__ pos_w,
    short* __restrict__ nx, short* __restrict__ uvqk_t,
    short* __restrict__ o_wt, short* __restrict__ bias) {
  __shared__ float tile[32][33];
  const int id = blockIdx.x;
  const int t = threadIdx.x;
  if (id < 4096) {
    // ---- bias[b][i][j] = pos_w[j-i+1023] + ts_w[bucket(ts[min(i+1,1023)]-ts[j])]
    const int b = id >> 10, i = id & 1023;
    int ie = i + 1; if (ie > 1023) ie = 1023;
    const int tse = ts[(b << 10) + ie];
    const int j0 = t * 4;
    int4 tj = *(const int4*)&ts[(b << 10) + j0];
    const int* tjp = (const int*)&tj;
    float ov[4];
#pragma unroll
    for (int e = 0; e < 4; ++e) {
      int dt = tse - tjp[e];
      float ad = fabsf((float)dt);
      if (ad < 1.f) ad = 1.f;
      int bkt = (int)(__logf(ad) * (1.f / 0.301f));
      if (bkt > 64) bkt = 64;
      ov[e] = pos_w[j0 + e - i + 1023] + ts_w[bkt];
    }
    uint2 o2 = {pk_bf16(ov[0], ov[1]), pk_bf16(ov[2], ov[3])};
    *(uint2*)&bias[((size_t)id << 10) + j0] = o2;
  } else if (id < 5120) {
    // ---- nx = LN(x), one wave per 512-row
    const int lane = t & 63;
    const int row = ((id - 4096) << 2) + (t >> 6);
    const int c0 = lane * 8;
    const float* xr = x + (size_t)row * 512;
    float v[8];
    *(float4*)&v[0] = *(const float4*)(xr + c0);
    *(float4*)&v[4] = *(const float4*)(xr + c0 + 4);
    float s = 0.f, sq = 0.f;
#pragma unroll
    for (int e = 0; e < 8; ++e) { s += v[e]; sq += v[e] * v[e]; }
#pragma unroll
    for (int off = 32; off > 0; off >>= 1) {
      s += __shfl_xor(s, off);
      sq += __shfl_xor(sq, off);
    }
    float m = s * (1.f / 512.f);
    float var = sq * (1.f / 512.f) - m * m;
    float rinv = rsqrtf(var + 1e-5f);
    float wv[8], bv[8];
    *(float4*)&wv[0] = *(const float4*)(ln_x_w + c0);
    *(float4*)&wv[4] = *(const float4*)(ln_x_w + c0 + 4);
    *(float4*)&bv[0] = *(const float4*)(ln_x_b + c0);
    *(float4*)&bv[4] = *(const float4*)(ln_x_b + c0 + 4);
    float o[8];
#pragma unroll
    for (int e = 0; e < 8; ++e) o[e] = (v[e] - m) * rinv * wv[e] + bv[e];
    uint4 o4 = {pk_bf16(o[0], o[1]), pk_bf16(o[2], o[3]),
                pk_bf16(o[4], o[5]), pk_bf16(o[6], o[7])};
    *(uint4*)(nx + (size_t)row * 512 + c0) = o4;
  } else {
    // ---- f32 -> bf16 transpose (uvqk: 512x2048 -> 2048x512; o_w: 512x512)
    const float* src; short* dst; int R, C, bc, br;
    if (id < 6144) {
      int idm = id - 5120;
      src = uvqk; dst = uvqk_t; R = 512; C = 2048;
      bc = (idm & 63) * 32; br = (idm >> 6) * 32;
    } else {
      int idm = id - 6144;
      src = o_w; dst = o_wt; R = 512; C = 512;
      bc = (idm & 15) * 32; br = (idm >> 4) * 32;
    }
    const int c = t & 31, r0 = t >> 5;
#pragma unroll
    for (int p = 0; p < 4; ++p) {
      int r = r0 + p * 8;
      tile[r][c] = src[(size_t)(br + r) * C + bc + c];
    }
    __syncthreads();
#pragma unroll
    for (int p = 0; p < 4; ++p) {
      int r = r0 + p * 8;
      dst[(size_t)(bc + r) * R + br + c] = f2bf(tile[c][r]);
    }
  }
}

// ---------------- K2: GEMM1 128x128 tile, BK=64 as 2x32 chunks ---------------
__global__ __launch_bounds__(256) void gemm1_kernel(
    const short* __restrict__ A, const short* __restrict__ Bt,
    short* __restrict__ u_buf, short* __restrict__ vt_buf,
    short* __restrict__ q_buf, short* __restrict__ k_buf) {
  __shared__ __align__(16) short As[2][128 * 32];
  __shared__ __align__(16) short Bs[2][128 * 32];
  const int t = threadIdx.x;
  const int lane = t & 63, w = t >> 6;
  const int quad = lane >> 4, l15 = lane & 15;
  const int m0 = blockIdx.x * 128, n0 = blockIdx.y * 128;
  const int wm = (w & 1) * 64, wn = (w >> 1) * 64;
  const int lr = lane >> 2, lc = (lane & 3) * 8;
  floatx4 acc[4][4];
#pragma unroll
  for (int i = 0; i < 4; ++i)
#pragma unroll
    for (int j = 0; j < 4; ++j) acc[i][j] = (floatx4){0.f, 0.f, 0.f, 0.f};

  for (int k0 = 0; k0 < 512; k0 += 64) {
    __syncthreads();
#pragma unroll
    for (int c = 0; c < 2; ++c)
#pragma unroll
      for (int p = 0; p < 2; ++p) {
        int ra = w * 32 + p * 16;
        gl_lds16(&A[(size_t)(m0 + ra + lr) * 512 + k0 + c * 32 + lc], &As[c][ra * 32]);
        gl_lds16(&Bt[(size_t)(n0 + ra + lr) * 512 + k0 + c * 32 + lc], &Bs[c][ra * 32]);
      }
    __syncthreads();
#pragma unroll
    for (int c = 0; c < 2; ++c) {
      short8 af[4], bfr[4];
#pragma unroll
      for (int mi = 0; mi < 4; ++mi) af[mi] = *(const short8*)&As[c][(wm + mi * 16 + l15) * 32 + quad * 8];
#pragma unroll
      for (int ni = 0; ni < 4; ++ni) bfr[ni] = *(const short8*)&Bs[c][(wn + ni * 16 + l15) * 32 + quad * 8];
#pragma unroll
      for (int mi = 0; mi < 4; ++mi)
#pragma unroll
        for (int ni = 0; ni < 4; ++ni)
          acc[mi][ni] = MFMA_BF16(af[mi], bfr[ni], acc[mi][ni], 0, 0, 0);
    }
  }
  const int seg = n0 >> 9, cbase = n0 & 511;
  if (seg == 0) {  // u: [row][512] bf16
#pragma unroll
    for (int mi = 0; mi < 4; ++mi)
#pragma unroll
      for (int ni = 0; ni < 4; ++ni) {
        int row0 = m0 + wm + mi * 16 + quad * 4;
        int c = cbase + wn + ni * 16 + l15;
        float v0 = silu_f(acc[mi][ni][0]), v1 = silu_f(acc[mi][ni][1]);
        float v2 = silu_f(acc[mi][ni][2]), v3 = silu_f(acc[mi][ni][3]);
        unsigned pa = pk_bf16(v0, v1), pb = pk_bf16(v2, v3);
        u_buf[(size_t)row0 * 512 + c] = lo16(pa);
        u_buf[(size_t)(row0 + 1) * 512 + c] = hi16(pa);
        u_buf[(size_t)(row0 + 2) * 512 + c] = lo16(pb);
        u_buf[(size_t)(row0 + 3) * 512 + c] = hi16(pb);
      }
  } else if (seg == 1) {  // v transposed & pre-scaled by 1/N: [b,h,d,n]
#pragma unroll
    for (int mi = 0; mi < 4; ++mi)
#pragma unroll
      for (int ni = 0; ni < 4; ++ni) {
        int c = cbase + wn + ni * 16 + l15;
        int h = c >> 6, d = c & 63;
        int row0 = m0 + wm + mi * 16 + quad * 4;
        int b_ = row0 >> 10, nb = row0 & 1023;
        float v0 = silu_f(acc[mi][ni][0]) * (1.f / 1024.f);
        float v1 = silu_f(acc[mi][ni][1]) * (1.f / 1024.f);
        float v2 = silu_f(acc[mi][ni][2]) * (1.f / 1024.f);
        float v3 = silu_f(acc[mi][ni][3]) * (1.f / 1024.f);
        uint2 sv = {pk_bf16(v0, v1), pk_bf16(v2, v3)};
        *(uint2*)&vt_buf[(((size_t)(b_ * 8 + h) * 64 + d) << 10) + nb] = sv;
      }
  } else {  // q or k: [b,h,n,d]
    short* dst = (seg == 2) ? q_buf : k_buf;
#pragma unroll
    for (int mi = 0; mi < 4; ++mi)
#pragma unroll
      for (int ni = 0; ni < 4; ++ni) {
        int row0 = m0 + wm + mi * 16 + quad * 4;
        int c = cbase + wn + ni * 16 + l15;
        int b_ = row0 >> 10, nb = row0 & 1023;
        size_t base = ((((size_t)(b_ * 8 + (c >> 6))) << 10) + nb) * 64 + (c & 63);
        float v0 = silu_f(acc[mi][ni][0]), v1 = silu_f(acc[mi][ni][1]);
        float v2 = silu_f(acc[mi][ni][2]), v3 = silu_f(acc[mi][ni][3]);
        unsigned pa = pk_bf16(v0, v1), pb = pk_bf16(v2, v3);
        dst[base] = lo16(pa);
        dst[base + 64] = hi16(pa);
        dst[base + 128] = lo16(pb);
        dst[base + 192] = hi16(pb);
      }
  }
}

// ---------------- K3: causal silu-attention, quadrant 32x32 MFMA -------------
// grid (32 bh, 8 pair, 4 jh), 1024 blocks, 4 blocks/CU.  Block = 64i x 64j per
// staged tile; 4 waves = 2(i) x 2(j) quadrants, each one 32x32 S^T subtile via
// swapped mfma_32x32x16 (P lane-local, cvt_pk + permlane32_swap, Q in regs).
// Bias[b][i][j] folded into QK acc-init (uint2 gather; pattern immaterial,
// R11 A/B).  j-half partial ao's combined via red_s LDS reduce per half.
__global__ __launch_bounds__(256, 4) void attn_kernel(
    const short* __restrict__ q_buf, const short* __restrict__ k_buf,
    const short* __restrict__ vt_buf, const short* __restrict__ bias_buf,
    short* __restrict__ ao_part) {
  __shared__ __align__(16) short k_s[64][72];
  __shared__ __align__(16) short vt_s[64][72];
  __shared__ __align__(16) float red_s[2][32][64];

  const int t = threadIdx.x;
  const int lane = t & 63, w = t >> 6;
  const int l31 = lane & 31, hh = lane >> 5, h8 = hh * 8;
  const int wi = w & 1, wj = w >> 1;
  const int bh = blockIdx.x, pair = blockIdx.y, jh = blockIdx.z;
  const int b = bh >> 3, hd = bh & 7;
  const short* qh = q_buf + (size_t)bh * 65536;
  const short* kh = k_buf + (size_t)bh * 65536;
  const short* vth = vt_buf + (size_t)bh * 65536;
  const int sr = t >> 2, sc = (t & 3) * 16;

#pragma unroll
  for (int half = 0; half < 2; ++half) {
    const int it = half ? (15 - pair) : pair;  // 64-row i-tile index
    const int i0 = it * 64;
    const int iw0 = i0 + wi * 32;  // this wave's i-stripe base
    const int ig = iw0 + l31;      // this lane's global i (S^T column)
    // Q fragments (B-operand) in registers: qf[kk] = Q[ig][kk*16 + h8 .. +7]
    short8 qf[4];
#pragma unroll
    for (int kk = 0; kk < 4; ++kk)
      qf[kk] = *(const short8*)&qh[(size_t)ig * 64 + kk * 16 + h8];
    const short* brow = bias_buf + (((size_t)(b * 1024 + ig)) << 10);
    // first j-tile prefetch into registers (in-bounds even when jh > it)
    float4 kr0, kr1, vr0, vr1;
    {
      int j0 = jh * 64;
      kr0 = *(const float4*)&kh[(size_t)(j0 + sr) * 64 + sc];
      kr1 = *(const float4*)&kh[(size_t)(j0 + sr) * 64 + sc + 8];
      vr0 = *(const float4*)&vth[(size_t)sr * 1024 + j0 + sc];
      vr1 = *(const float4*)&vth[(size_t)sr * 1024 + j0 + sc + 8];
    }
    floatx16 ao0, ao1;
#pragma unroll
    for (int r = 0; r < 16; ++r) { ao0[r] = 0.f; ao1[r] = 0.f; }

    for (int jt = jh; jt <= it; jt += 4) {
      const int j0w = jt * 64 + wj * 32;    // this wave's j-quadrant base
      const bool live = (j0w <= iw0 + 31);
      const bool needmask = live && (j0w + 31 > iw0);
      uint2 bw[4];
      if (live) {
#pragma unroll
        for (int g = 0; g < 4; ++g)
          bw[g] = *(const uint2*)&brow[j0w + g * 8 + hh * 4];
      }
      __syncthreads();  // prev tile's k_s/vt_s MFMA reads done
      *(float4*)&k_s[sr][sc] = kr0;
      *(float4*)&k_s[sr][sc + 8] = kr1;
      *(float4*)&vt_s[sr][sc] = vr0;
      *(float4*)&vt_s[sr][sc + 8] = vr1;
      {  // prefetch next tile (clamped redundant reload on last iter)
        int jn = (jt + 4 <= it) ? jt + 4 : jt;
        int jn0 = jn * 64;
        kr0 = *(const float4*)&kh[(size_t)(jn0 + sr) * 64 + sc];
        kr1 = *(const float4*)&kh[(size_t)(jn0 + sr) * 64 + sc + 8];
        vr0 = *(const float4*)&vth[(size_t)sr * 1024 + jn0 + sc];
        vr1 = *(const float4*)&vth[(size_t)sr * 1024 + jn0 + sc + 8];
      }
      __syncthreads();  // staged k_s/vt_s visible
      if (!live) continue;  // quadrant above the diagonal
      __builtin_amdgcn_s_setprio(1);
      // ---- S^T = bias + K q^T  (acc row = j_local crow(r,hh), col = i) ----
      floatx16 s;
#pragma unroll
      for (int g = 0; g < 4; ++g) {
        s[4 * g + 0] = bflo(bw[g].x);
        s[4 * g + 1] = bfhi(bw[g].x);
        s[4 * g + 2] = bflo(bw[g].y);
        s[4 * g + 3] = bfhi(bw[g].y);
      }
#pragma unroll
      for (int kk = 0; kk < 4; ++kk) {
        short8 ak = *(const short8*)&k_s[wj * 32 + l31][kk * 16 + h8];
        s = MFMA32(ak, qf[kk], s, 0, 0, 0);
      }
      // ---- P = silu(S), causal (zero where j > i) ----
      float p[16];
#pragma unroll
      for (int r = 0; r < 16; ++r) {
        float xv = s[r];
        float pv = xv / (1.f + __expf(-xv));
        if (needmask) {
          int jg = j0w + hh * 4 + (r & 3) + 8 * (r >> 2);
          if (jg > ig) pv = 0.f;
        }
        p[r] = pv;
      }
      // ---- P -> bf16 A-fragments (cvt_pk + permlane32_swap) ----
      unsigned X0 = pk_bf16(p[0], p[1]), Y0 = pk_bf16(p[2], p[3]);
      unsigned X1 = pk_bf16(p[4], p[5]), Y1 = pk_bf16(p[6], p[7]);
      unsigned X2 = pk_bf16(p[8], p[9]), Y2 = pk_bf16(p[10], p[11]);
      unsigned X3 = pk_bf16(p[12], p[13]), Y3 = pk_bf16(p[14], p[15]);
      permswap(X0, X1);
      permswap(Y0, Y1);
      permswap(X2, X3);
      permswap(Y2, Y3);
      short8 pa0 = mk8(X0, Y0, X1, Y1);  // k-chunk j_local [0,16)
      short8 pa1 = mk8(X2, Y2, X3, Y3);  // k-chunk j_local [16,32)
      // ---- ao += P @ (v/N) ----
#pragma unroll
      for (int c = 0; c < 2; ++c) {
        short8 pa = c ? pa1 : pa0;
        short8 bv0 = *(const short8*)&vt_s[l31][wj * 32 + c * 16 + h8];
        short8 bv1 = *(const short8*)&vt_s[32 + l31][wj * 32 + c * 16 + h8];
        ao0 = MFMA32(pa, bv0, ao0, 0, 0, 0);
        ao1 = MFMA32(pa, bv1, ao1, 0, 0, 0);
      }
      __builtin_amdgcn_s_setprio(0);
    }
    // ---- cross-wave reduce of the two j-half partials, then store ----
    __syncthreads();  // also protects red_s from the previous half
    if (wj == 1) {
#pragma unroll
      for (int r = 0; r < 16; ++r) {
        int il = (r & 3) + 8 * (r >> 2) + 4 * hh;
        red_s[wi][il][l31] = ao0[r];
        red_s[wi][il][32 + l31] = ao1[r];
      }
    }
    __syncthreads();
    if (wj == 0) {
      short* aod = ao_part + (size_t)jh * 2097152;
#pragma unroll
      for (int r = 0; r < 16; ++r) {
        int il = (r & 3) + 8 * (r >> 2) + 4 * hh;
        float a0 = ao0[r] + red_s[wi][il][l31];
        float a1 = ao1[r] + red_s[wi][il][32 + l31];
        int gi = iw0 + il;
        size_t base = ((size_t)(b * 1024 + gi)) * 512 + hd * 64 + l31;
        aod[base] = f2bf(a0);
        aod[base + 32] = f2bf(a1);
      }
    }
  }
}

// ---------------- K4: g = u * LN_a(ao0+ao1+ao2+ao3) -> bf16 ------------------
__global__ __launch_bounds__(256) void ln_mul_kernel(
    const short* __restrict__ ao_part, const short* __restrict__ u,
    const float* __restrict__ w_, const float* __restrict__ b_,
    short* __restrict__ g) {
  const int lane = threadIdx.x & 63;
  const int row = (blockIdx.x << 2) + (threadIdx.x >> 6);
  const int c0 = lane * 8;
  short8 a0 = *(const short8*)(ao_part + (size_t)row * 512 + c0);
  short8 a1 = *(const short8*)(ao_part + 2097152 + (size_t)row * 512 + c0);
  short8 a2 = *(const short8*)(ao_part + 4194304 + (size_t)row * 512 + c0);
  short8 a3 = *(const short8*)(ao_part + 6291456 + (size_t)row * 512 + c0);
  float v[8];
#pragma unroll
  for (int e = 0; e < 8; ++e)
    v[e] = (bf2f(a0[e]) + bf2f(a1[e])) + (bf2f(a2[e]) + bf2f(a3[e]));
  float s = 0.f, sq = 0.f;
#pragma unroll
  for (int e = 0; e < 8; ++e) { s += v[e]; sq += v[e] * v[e]; }
#pragma unroll
  for (int off = 32; off > 0; off >>= 1) {
    s += __shfl_xor(s, off);
    sq += __shfl_xor(sq, off);
  }
  float m = s * (1.f / 512.f);
  float var = sq * (1.f / 512.f) - m * m;
  float rinv = rsqrtf(var + 1e-5f);
  float wv[8], bv[8];
  *(float4*)&wv[0] = *(const float4*)(w_ + c0);
  *(float4*)&wv[4] = *(const float4*)(w_ + c0 + 4);
  *(float4*)&bv[0] = *(const float4*)(b_ + c0);
  *(float4*)&bv[4] = *(const float4*)(b_ + c0 + 4);
  short8 uv = *(const short8*)(u + (size_t)row * 512 + c0);
  float o[8];
#pragma unroll
  for (int e = 0; e < 8; ++e)
    o[e] = bf2f(uv[e]) * ((v[e] - m) * rinv * wv[e] + bv[e]);
  uint4 o4 = {pk_bf16(o[0], o[1]), pk_bf16(o[2], o[3]),
              pk_bf16(o[4], o[5]), pk_bf16(o[6], o[7])};
  *(uint4*)(g + (size_t)row * 512 + c0) = o4;
}

// ---------------- K5: GEMM2 64x64 tiles, grid 512 ----------------------------
__global__ __launch_bounds__(256) void gemm2_kernel(
    const short* __restrict__ G, const short* __restrict__ Wt,
    const float* __restrict__ o_b, const float* __restrict__ x,
    float* __restrict__ out) {
  __shared__ __align__(16) short As[2][64 * 32];
  __shared__ __align__(16) short Bs[2][64 * 32];
  const int t = threadIdx.x;
  const int lane = t & 63, w = t >> 6;
  const int quad = lane >> 4, l15 = lane & 15;
  const int m0 = blockIdx.x * 64, n0 = blockIdx.y * 64;
  const int lr = lane >> 2, lc = (lane & 3) * 8;
  floatx4 acc[4];
#pragma unroll
  for (int j = 0; j < 4; ++j) acc[j] = (floatx4){0.f, 0.f, 0.f, 0.f};

  for (int k0 = 0; k0 < 512; k0 += 64) {
    __syncthreads();
#pragma unroll
    for (int c = 0; c < 2; ++c) {
      int ra = w * 16;
      gl_lds16(&G[(size_t)(m0 + ra + lr) * 512 + k0 + c * 32 + lc], &As[c][ra * 32]);
      gl_lds16(&Wt[(size_t)(n0 + ra + lr) * 512 + k0 + c * 32 + lc], &Bs[c][ra * 32]);
    }
    __syncthreads();
#pragma unroll
    for (int c = 0; c < 2; ++c) {
      short8 af = *(const short8*)&As[c][(w * 16 + l15) * 32 + quad * 8];
#pragma unroll
      for (int ni = 0; ni < 4; ++ni) {
        short8 bfr = *(const short8*)&Bs[c][(ni * 16 + l15) * 32 + quad * 8];
        acc[ni] = MFMA_BF16(af, bfr, acc[ni], 0, 0, 0);
      }
    }
  }
#pragma unroll
  for (int ni = 0; ni < 4; ++ni)
#pragma unroll
    for (int r = 0; r < 4; ++r) {
      int row = m0 + w * 16 + quad * 4 + r;
      int c = n0 + ni * 16 + l15;
      out[(size_t)row * 512 + c] = acc[ni][r] + o_b[c] + x[(size_t)row * 512 + c];
    }
}

extern "C" void kernel_launch(void* const* d_in, const int* in_sizes, int n_in,
                              void* d_out, int out_size, void* d_ws, size_t ws_size,
                              hipStream_t stream) {
  const float* x = (const float*)d_in[0];
  const int* ts = (const int*)d_in[1];
  // d_in[2] = cm (triu, inline), d_in[3] = pm (all false, ignored)
  const float* uvqk = (const float*)d_in[4];
  const float* o_w = (const float*)d_in[5];
  const float* o_b = (const float*)d_in[6];
  const float* ln_x_w = (const float*)d_in[7];
  const float* ln_x_b = (const float*)d_in[8];
  const float* ln_a_w = (const float*)d_in[9];
  const float* ln_a_b = (const float*)d_in[10];
  const float* ts_w = (const float*)d_in[11];
  const float* pos_w = (const float*)d_in[12];
  float* out = (float*)d_out;

  char* ws = (char*)d_ws;
  short* nx = (short*)(ws + 0);              // 4096x512 bf16 (4 MB); reused as g after gemm1
  short* uvqk_t = (short*)(ws + 4194304);    // 2048x512 bf16 (2 MB)
  short* o_wt = (short*)(ws + 6291456);      // 512x512 bf16 (0.5 MB)
  short* u_buf = (short*)(ws + 6815744);     // 4096x512 bf16 (4 MB)
  short* q_buf = (short*)(ws + 11010048);    // [B,H,N,64] bf16 (4 MB)
  short* k_buf = (short*)(ws + 15204352);    // [B,H,N,64] bf16 (4 MB)
  short* vt_buf = (short*)(ws + 19398656);   // [B,H,64,N] bf16 (4 MB)
  short* bias_buf = (short*)(ws + 23592960); // bias [B,N,N] bf16 (8 MB)
  short* ao_part = (short*)(ws + 31981568);  // 4 x [B,N,512] bf16 (16 MB)
  short* g_buf = nx;

  hipLaunchKernelGGL(prep_kernel, dim3(6400), dim3(256), 0, stream,
                     x, ts, uvqk, o_w, ln_x_w, ln_x_b, ts_w, pos_w,
                     nx, uvqk_t, o_wt, bias_buf);
  hipLaunchKernelGGL(gemm1_kernel, dim3(32, 16), dim3(256), 0, stream, nx, uvqk_t, u_buf, vt_buf, q_buf, k_buf);
  hipLaunchKernelGGL(attn_kernel, dim3(32, 8, 4), dim3(256), 0, stream, q_buf, k_buf, vt_buf, bias_buf, ao_part);
  hipLaunchKernelGGL(ln_mul_kernel, dim3(1024), dim3(256), 0, stream, ao_part, u_buf, ln_a_w, ln_a_b, g_buf);
  hipLaunchKernelGGL(gemm2_kernel, dim3(64, 8), dim3(256), 0, stream, g_buf, o_wt, o_b, x, out);
}